// Round 1
// baseline (199.994 us; speedup 1.0000x reference)
//
#include <hip/hip_runtime.h>

typedef __attribute__((ext_vector_type(4))) float f32x4;
typedef __attribute__((ext_vector_type(8))) short bf16x8;

#define D_MODEL 1024
#define NQK     2048   // q cols (0..1023, pre-scaled) + k cols (1024..2047)
#define MTOK    8192   // B*L
#define HD      256
#define LSEQ    2048
#define NB      4

__device__ inline unsigned short f2bf(float f) {
  unsigned u = __float_as_uint(f);
  unsigned r = (u + 0x7FFFu + ((u >> 16) & 1u)) >> 16;
  return (unsigned short)r;
}

__device__ inline void gl_lds16(const void* g, void* l) {
  __builtin_amdgcn_global_load_lds((const __attribute__((address_space(1))) void*)g,
                                   (__attribute__((address_space(3))) void*)l, 16, 0, 0);
}

// ---------------- fp32 -> bf16 convert (vectorized) ----------------
__global__ __launch_bounds__(256) void f32_to_bf16_kernel(
    const float4* __restrict__ src, ushort4* __restrict__ dst) {
  int i = blockIdx.x * 256 + threadIdx.x;
  float4 v = src[i];
  ushort4 o;
  o.x = f2bf(v.x); o.y = f2bf(v.y); o.z = f2bf(v.z); o.w = f2bf(v.w);
  dst[i] = o;
}

// ---------------- GEMM: C[m][n] = sum_k Xb[m][k]*Wb[n][k]; +bias, q-scale, bf16 store ----------------
__global__ __launch_bounds__(256) void gemm_qk(
    const unsigned short* __restrict__ Xb,   // [8192][1024] bf16
    const unsigned short* __restrict__ Wb,   // [2048][1024] bf16
    const float* __restrict__ bias,          // [3072]
    unsigned short* __restrict__ C)          // [8192][2048] bf16
{
  __shared__ unsigned short As[128 * 32];  // 8KB
  __shared__ unsigned short Bs[128 * 32];  // 8KB
  int t = threadIdx.x;
  int w = t >> 6, lane = t & 63;
  int l15 = lane & 15, lg = lane >> 4;
  int m0 = blockIdx.y * 128, n0 = blockIdx.x * 128;
  int wm = (w >> 1) * 64, wn = (w & 1) * 64;
  f32x4 acc[4][4] = {};

  for (int kt = 0; kt < D_MODEL / 32; ++kt) {
#pragma unroll
    for (int i = 0; i < 2; ++i) {
      int ob = w * 1024 + i * 4096;        // wave-uniform LDS base
      int o = ob + lane * 16;              // this lane's slot
      int row = o >> 6;
      int kb = (o & 63) ^ (((row >> 1) & 3) << 4);   // inverse-swizzled source
      gl_lds16(Xb + (m0 + row) * D_MODEL + kt * 32 + (kb >> 1), (char*)As + ob);
      gl_lds16(Wb + (n0 + row) * D_MODEL + kt * 32 + (kb >> 1), (char*)Bs + ob);
    }
    __syncthreads();
    bf16x8 a[4], b[4];
#pragma unroll
    for (int mi = 0; mi < 4; mi++) {
      int row = wm + mi * 16 + l15;
      int kb = (lg * 16) ^ (((row >> 1) & 3) << 4);
      a[mi] = *(const bf16x8*)((const char*)As + row * 64 + kb);
    }
#pragma unroll
    for (int ni = 0; ni < 4; ni++) {
      int row = wn + ni * 16 + l15;
      int kb = (lg * 16) ^ (((row >> 1) & 3) << 4);
      b[ni] = *(const bf16x8*)((const char*)Bs + row * 64 + kb);
    }
#pragma unroll
    for (int mi = 0; mi < 4; mi++)
#pragma unroll
      for (int ni = 0; ni < 4; ni++)
        acc[mi][ni] = __builtin_amdgcn_mfma_f32_16x16x32_bf16(a[mi], b[ni], acc[mi][ni], 0, 0, 0);
    __syncthreads();
  }

#pragma unroll
  for (int ni = 0; ni < 4; ni++) {
    int n = n0 + wn + ni * 16 + l15;
    float bv = bias[n];
    float scale = (n < 1024) ? 0.0625f : 1.0f;   // fold 1/sqrt(hd) into Q
#pragma unroll
    for (int mi = 0; mi < 4; mi++) {
      int mbase = m0 + wm + mi * 16 + lg * 4;
#pragma unroll
      for (int r = 0; r < 4; r++) {
        float v = (acc[mi][ni][r] + bv) * scale;
        C[(mbase + r) * NQK + n] = f2bf(v);
      }
    }
  }
}

// ---------------- attention column sums (two-pass online softmax) ----------------
__global__ __launch_bounds__(256) void attn_colsum(
    const unsigned short* __restrict__ C,  // [8192][2048] bf16
    float* __restrict__ colsum)            // [4][2048]
{
  __shared__ unsigned short Ks[128 * 256]; // 64KB: [128 keys][256 d] swizzled
  int t = threadIdx.x, w = t >> 6, lane = t & 63;
  int wm = w >> 1, wn = w & 1;
  int id = blockIdx.x;
  int qb = id & 31, h = (id >> 5) & 3, b = id >> 7;
  int l15 = lane & 15, lg = lane >> 4;

  // Q fragments: wave owns 32 query rows (2 m-frags), held in registers
  bf16x8 qf[2][8];
  int qrowbase = b * LSEQ + qb * 64 + wm * 32;
#pragma unroll
  for (int mi = 0; mi < 2; mi++)
#pragma unroll
    for (int kk = 0; kk < 8; kk++)
      qf[mi][kk] = *(const bf16x8*)(C + (qrowbase + mi * 16 + l15) * NQK + h * HD + kk * 32 + lg * 8);

  float m[2][4], Z[2][4], invZ[2][4];
#pragma unroll
  for (int mi = 0; mi < 2; mi++)
#pragma unroll
    for (int r = 0; r < 4; r++) { m[mi][r] = -1e30f; Z[mi][r] = 0.f; invZ[mi][r] = 0.f; }

  const unsigned short* Kbase = C + (size_t)(b * LSEQ) * NQK + 1024 + h * HD;

  for (int pass = 0; pass < 2; ++pass) {
    for (int tile = 0; tile < 16; ++tile) {
      int s0 = tile * 128;
      // stage K tile: 128 keys x 512B, XOR-swizzled via pre-swizzled global source
#pragma unroll
      for (int i = 0; i < 16; i++) {
        int ob = w * 1024 + i * 4096;
        int o = ob + lane * 16;
        int s = o >> 9;
        int db = (o & 511) ^ ((s & 7) << 4);
        gl_lds16(Kbase + (s0 + s) * NQK + (db >> 1), (char*)Ks + ob);
      }
      __syncthreads();

      f32x4 acc[2][4] = {};
#pragma unroll
      for (int n = 0; n < 4; n++) {
        int srow = wn * 64 + n * 16 + l15;
        int rb = srow * 512;
        int sw = (srow & 7) << 4;
#pragma unroll
        for (int kk = 0; kk < 8; kk++) {
          bf16x8 kf = *(const bf16x8*)((const char*)Ks + rb + ((kk * 64 + lg * 16) ^ sw));
#pragma unroll
          for (int mi = 0; mi < 2; mi++)
            acc[mi][n] = __builtin_amdgcn_mfma_f32_16x16x32_bf16(qf[mi][kk], kf, acc[mi][n], 0, 0, 0);
        }
      }

      if (pass == 0) {
#pragma unroll
        for (int mi = 0; mi < 2; mi++)
#pragma unroll
          for (int r = 0; r < 4; r++) {
            float mx = fmaxf(fmaxf(acc[mi][0][r], acc[mi][1][r]), fmaxf(acc[mi][2][r], acc[mi][3][r]));
#pragma unroll
            for (int off = 1; off < 16; off <<= 1) mx = fmaxf(mx, __shfl_xor(mx, off, 64));
            float nm = fmaxf(m[mi][r], mx);
            float sum = 0.f;
#pragma unroll
            for (int n = 0; n < 4; n++) sum += __expf(acc[mi][n][r] - nm);
#pragma unroll
            for (int off = 1; off < 16; off <<= 1) sum += __shfl_xor(sum, off, 64);
            Z[mi][r] = Z[mi][r] * __expf(m[mi][r] - nm) + sum;
            m[mi][r] = nm;
          }
      } else {
#pragma unroll
        for (int n = 0; n < 4; n++) {
          float c = 0.f;
#pragma unroll
          for (int mi = 0; mi < 2; mi++)
#pragma unroll
            for (int r = 0; r < 4; r++)
              c += __expf(acc[mi][n][r] - m[mi][r]) * invZ[mi][r];
          c += __shfl_xor(c, 16, 64);
          c += __shfl_xor(c, 32, 64);
          if (lane < 16)
            atomicAdd(&colsum[b * LSEQ + s0 + wn * 64 + n * 16 + lane], c);
        }
      }
      __syncthreads();
    }

    if (pass == 0) {
      // combine running (m,Z) across the two key-split waves via LDS (reuses Ks)
      float* cb = (float*)Ks;
      if (l15 == 0) {
#pragma unroll
        for (int mi = 0; mi < 2; mi++)
#pragma unroll
          for (int r = 0; r < 4; r++) {
            int idx = (wm * 2 + wn) * 32 + mi * 16 + lg * 4 + r;
            cb[idx] = m[mi][r];
            cb[128 + idx] = Z[mi][r];
          }
      }
      __syncthreads();
#pragma unroll
      for (int mi = 0; mi < 2; mi++)
#pragma unroll
        for (int r = 0; r < 4; r++) {
          int i0 = (wm * 2 + 0) * 32 + mi * 16 + lg * 4 + r;
          int i1 = (wm * 2 + 1) * 32 + mi * 16 + lg * 4 + r;
          float ma = cb[i0], mb2 = cb[i1];
          float za = cb[128 + i0], zb = cb[128 + i1];
          float nm = fmaxf(ma, mb2);
          float zz = za * __expf(ma - nm) + zb * __expf(mb2 - nm);
          m[mi][r] = nm;
          invZ[mi][r] = 1.0f / zz;
        }
      __syncthreads();
    }
  }
}

// ---------------- zero + finalize ----------------
__global__ __launch_bounds__(256) void zero_kernel(float* __restrict__ p, int n) {
  int i = blockIdx.x * 256 + threadIdx.x;
  if (i < n) p[i] = 0.f;
}

__global__ __launch_bounds__(256) void finalize_kernel(
    const float* __restrict__ colsum, float* __restrict__ out) {
  __shared__ float red[256];
  int t = threadIdx.x;
  float acc = 0.f;
  for (int i = t; i < NB * LSEQ; i += 256) {
    float aw = colsum[i] * (1.0f / 8192.0f) + 1e-8f;
    acc += -aw * __logf(aw);
  }
  red[t] = acc;
  __syncthreads();
  for (int s = 128; s > 0; s >>= 1) {
    if (t < s) red[t] += red[t + s];
    __syncthreads();
  }
  if (t == 0) {
    float me = red[0] * 0.25f;
    out[0] = 1.0f / (1.0f + __expf(-me));
  }
}

extern "C" void kernel_launch(void* const* d_in, const int* in_sizes, int n_in,
                              void* d_out, int out_size, void* d_ws, size_t ws_size,
                              hipStream_t stream) {
  const float* hs   = (const float*)d_in[0];   // [4,2048,1024]
  const float* wgt  = (const float*)d_in[1];   // [3072,1024]
  const float* bias = (const float*)d_in[2];   // [3072]
  float* out = (float*)d_out;
  char* ws = (char*)d_ws;

  unsigned short* Xb  = (unsigned short*)(ws);                        // 16 MB
  unsigned short* Wb  = (unsigned short*)(ws + (16u << 20));          // 4 MB
  unsigned short* Cqk = (unsigned short*)(ws + (20u << 20));          // 32 MB
  float* colsum = (float*)(ws + (54u << 20));                         // 32 KB

  f32_to_bf16_kernel<<<8192, 256, 0, stream>>>((const float4*)hs, (ushort4*)Xb);
  f32_to_bf16_kernel<<<2048, 256, 0, stream>>>((const float4*)wgt, (ushort4*)Wb);

  dim3 g1(16, 64);
  gemm_qk<<<g1, 256, 0, stream>>>(Xb, Wb, bias, Cqk);

  zero_kernel<<<32, 256, 0, stream>>>(colsum, NB * LSEQ);
  attn_colsum<<<512, 256, 0, stream>>>(Cqk, colsum);
  finalize_kernel<<<1, 256, 0, stream>>>(colsum, out);
}

// Round 2
// 188.712 us; speedup vs baseline: 1.0598x; 1.0598x over previous
//
#include <hip/hip_runtime.h>

typedef __attribute__((ext_vector_type(4))) float f32x4;
typedef __attribute__((ext_vector_type(8))) short bf16x8;

#define D_MODEL 1024
#define NQK     2048   // q cols (0..1023, pre-scaled) + k cols (1024..2047)
#define MTOK    8192   // B*L
#define HD      256
#define LSEQ    2048
#define NB      4

__device__ inline unsigned short f2bf(float f) {
  unsigned u = __float_as_uint(f);
  unsigned r = (u + 0x7FFFu + ((u >> 16) & 1u)) >> 16;
  return (unsigned short)r;
}

__device__ inline float bf2f(unsigned short v) {
  return __uint_as_float(((unsigned)v) << 16);
}

__device__ inline void gl_lds16(const void* g, void* l) {
  __builtin_amdgcn_global_load_lds((const __attribute__((address_space(1))) void*)g,
                                   (__attribute__((address_space(3))) void*)l, 16, 0, 0);
}

// ---------------- fp32 -> bf16 convert (vectorized) ----------------
__global__ __launch_bounds__(256) void f32_to_bf16_kernel(
    const float4* __restrict__ src, ushort4* __restrict__ dst) {
  int i = blockIdx.x * 256 + threadIdx.x;
  float4 v = src[i];
  ushort4 o;
  o.x = f2bf(v.x); o.y = f2bf(v.y); o.z = f2bf(v.z); o.w = f2bf(v.w);
  dst[i] = o;
}

// ---------------- GEMM: C[m][n] = sum_k Xb[m][k]*Wb[n][k]; +bias, q-scale, bf16 store ----------------
__global__ __launch_bounds__(256) void gemm_qk(
    const unsigned short* __restrict__ Xb,   // [8192][1024] bf16
    const unsigned short* __restrict__ Wb,   // [2048][1024] bf16
    const float* __restrict__ bias,          // [3072]
    unsigned short* __restrict__ C)          // [8192][2048] bf16
{
  __shared__ unsigned short As[128 * 32];  // 8KB
  __shared__ unsigned short Bs[128 * 32];  // 8KB
  int t = threadIdx.x;
  int w = t >> 6, lane = t & 63;
  int l15 = lane & 15, lg = lane >> 4;
  int m0 = blockIdx.y * 128, n0 = blockIdx.x * 128;
  int wm = (w >> 1) * 64, wn = (w & 1) * 64;
  f32x4 acc[4][4] = {};

  for (int kt = 0; kt < D_MODEL / 32; ++kt) {
#pragma unroll
    for (int i = 0; i < 2; ++i) {
      int ob = w * 1024 + i * 4096;        // wave-uniform LDS base
      int o = ob + lane * 16;              // this lane's slot
      int row = o >> 6;
      int kb = (o & 63) ^ (((row >> 1) & 3) << 4);   // inverse-swizzled source
      gl_lds16(Xb + (m0 + row) * D_MODEL + kt * 32 + (kb >> 1), (char*)As + ob);
      gl_lds16(Wb + (n0 + row) * D_MODEL + kt * 32 + (kb >> 1), (char*)Bs + ob);
    }
    __syncthreads();
    bf16x8 a[4], b[4];
#pragma unroll
    for (int mi = 0; mi < 4; mi++) {
      int row = wm + mi * 16 + l15;
      int kb = (lg * 16) ^ (((row >> 1) & 3) << 4);
      a[mi] = *(const bf16x8*)((const char*)As + row * 64 + kb);
    }
#pragma unroll
    for (int ni = 0; ni < 4; ni++) {
      int row = wn + ni * 16 + l15;
      int kb = (lg * 16) ^ (((row >> 1) & 3) << 4);
      b[ni] = *(const bf16x8*)((const char*)Bs + row * 64 + kb);
    }
#pragma unroll
    for (int mi = 0; mi < 4; mi++)
#pragma unroll
      for (int ni = 0; ni < 4; ni++)
        acc[mi][ni] = __builtin_amdgcn_mfma_f32_16x16x32_bf16(a[mi], b[ni], acc[mi][ni], 0, 0, 0);
    __syncthreads();
  }

#pragma unroll
  for (int ni = 0; ni < 4; ni++) {
    int n = n0 + wn + ni * 16 + l15;
    float bv = bias[n];
    float scale = (n < 1024) ? 0.0625f : 1.0f;   // fold 1/sqrt(hd) into Q
#pragma unroll
    for (int mi = 0; mi < 4; mi++) {
      int mbase = m0 + wm + mi * 16 + lg * 4;
#pragma unroll
      for (int r = 0; r < 4; r++) {
        float v = (acc[mi][ni][r] + bv) * scale;
        C[(mbase + r) * NQK + n] = f2bf(v);
      }
    }
  }
}

// ---------------- pass A: QK^T once, E=exp(S) stored bf16 (fragment order), Z row sums ----------------
__global__ __launch_bounds__(256) void attn_exp(
    const unsigned short* __restrict__ C,  // [8192][2048] bf16
    unsigned short* __restrict__ E,        // [16][32][16][256][32] bf16 fragment-packed
    float* __restrict__ Zbuf)              // [16][2048]
{
  __shared__ unsigned short Ks[128 * 256]; // 64KB: [128 keys][256 d] swizzled
  int t = threadIdx.x, w = t >> 6, lane = t & 63;
  int wm = w >> 1, wn = w & 1;
  int id = blockIdx.x;
  int qb = id & 31, h = (id >> 5) & 3, b = id >> 7;
  int bh = b * 4 + h;
  int l15 = lane & 15, lg = lane >> 4;

  // Q fragments: wave owns 32 query rows (2 m-frags), held in registers
  bf16x8 qf[2][8];
  int qrowbase = b * LSEQ + qb * 64 + wm * 32;
#pragma unroll
  for (int mi = 0; mi < 2; mi++)
#pragma unroll
    for (int kk = 0; kk < 8; kk++)
      qf[mi][kk] = *(const bf16x8*)(C + (qrowbase + mi * 16 + l15) * NQK + h * HD + kk * 32 + lg * 8);

  float zacc[2][4] = {};

  const unsigned short* Kbase = C + (size_t)(b * LSEQ) * NQK + 1024 + h * HD;

  for (int tile = 0; tile < 16; ++tile) {
    // stage K tile: 128 keys x 512B, XOR-swizzled via pre-swizzled global source
#pragma unroll
    for (int i = 0; i < 16; i++) {
      int ob = w * 1024 + i * 4096;
      int o = ob + lane * 16;
      int s = o >> 9;
      int db = (o & 511) ^ ((s & 7) << 4);
      gl_lds16(Kbase + (tile * 128 + s) * NQK + (db >> 1), (char*)Ks + ob);
    }
    __syncthreads();

    f32x4 acc[2][4] = {};
#pragma unroll
    for (int n = 0; n < 4; n++) {
      int srow = wn * 64 + n * 16 + l15;
      int rb = srow * 512;
      int sw = (srow & 7) << 4;
#pragma unroll
      for (int kk = 0; kk < 8; kk++) {
        bf16x8 kf = *(const bf16x8*)((const char*)Ks + rb + ((kk * 64 + lg * 16) ^ sw));
#pragma unroll
        for (int mi = 0; mi < 2; mi++)
          acc[mi][n] = __builtin_amdgcn_mfma_f32_16x16x32_bf16(qf[mi][kk], kf, acc[mi][n], 0, 0, 0);
      }
    }

    // exp, pack to bf16 in fragment-native order, accumulate row sums
    unsigned short vals[32];
#pragma unroll
    for (int mi = 0; mi < 2; mi++)
#pragma unroll
      for (int n = 0; n < 4; n++)
#pragma unroll
        for (int r = 0; r < 4; r++) {
          float e = __expf(acc[mi][n][r]);
          vals[mi * 16 + n * 4 + r] = f2bf(e);
          zacc[mi][r] += e;
        }
    {
      size_t eoff = ((((size_t)bh * 32 + qb) * 16 + tile) * 256 + t) * 32;
      const uint4* vv = (const uint4*)vals;
      uint4* dst = (uint4*)(E + eoff);
      dst[0] = vv[0]; dst[1] = vv[1]; dst[2] = vv[2]; dst[3] = vv[3];
    }
    __syncthreads();
  }

  // reduce Z across the 16 l15 lanes (same row), then one atomic per row per wave
#pragma unroll
  for (int mi = 0; mi < 2; mi++)
#pragma unroll
    for (int r = 0; r < 4; r++) {
      float z = zacc[mi][r];
      z += __shfl_xor(z, 1, 64);
      z += __shfl_xor(z, 2, 64);
      z += __shfl_xor(z, 4, 64);
      z += __shfl_xor(z, 8, 64);
      if (l15 == 0) {
        int row = qb * 64 + wm * 32 + mi * 16 + lg * 4 + r;
        atomicAdd(&Zbuf[bh * LSEQ + row], z);
      }
    }
}

// ---------------- pass B: stream E (L3-resident), scale by invZ, column-reduce ----------------
__global__ __launch_bounds__(256) void attn_colsum2(
    const unsigned short* __restrict__ E,
    const float* __restrict__ Zbuf,
    float* __restrict__ colsum)            // [4][2048]
{
  int t = threadIdx.x, w = t >> 6, lane = t & 63;
  int wm = w >> 1, wn = w & 1;
  int id = blockIdx.x;
  int qb = id & 31, h = (id >> 5) & 3, b = id >> 7;
  int bh = b * 4 + h;
  int l15 = lane & 15, lg = lane >> 4;

  float invz[2][4];
#pragma unroll
  for (int mi = 0; mi < 2; mi++)
#pragma unroll
    for (int r = 0; r < 4; r++) {
      int row = qb * 64 + wm * 32 + mi * 16 + lg * 4 + r;
      invz[mi][r] = 1.0f / Zbuf[bh * LSEQ + row];
    }

  for (int tile = 0; tile < 16; ++tile) {
    size_t eoff = ((((size_t)bh * 32 + qb) * 16 + tile) * 256 + t) * 32;
    const uint4* src = (const uint4*)(E + eoff);
    uint4 v0 = src[0], v1 = src[1], v2 = src[2], v3 = src[3];
    const unsigned short* vals = (const unsigned short*)&v0; // relies on contiguity? no — handle per-vec
    uint4 vv[4] = {v0, v1, v2, v3};
    const unsigned short* vs = (const unsigned short*)vv;

    float c[4] = {};
#pragma unroll
    for (int mi = 0; mi < 2; mi++)
#pragma unroll
      for (int n = 0; n < 4; n++)
#pragma unroll
        for (int r = 0; r < 4; r++)
          c[n] += bf2f(vs[mi * 16 + n * 4 + r]) * invz[mi][r];

#pragma unroll
    for (int n = 0; n < 4; n++) {
      float cc = c[n];
      cc += __shfl_xor(cc, 16, 64);
      cc += __shfl_xor(cc, 32, 64);
      if (lane < 16)
        atomicAdd(&colsum[b * LSEQ + tile * 128 + wn * 64 + n * 16 + lane], cc);
    }
    (void)vals;
  }
}

// ---------------- zero + finalize ----------------
__global__ __launch_bounds__(256) void zero_kernel(float* __restrict__ p, int n) {
  int i = blockIdx.x * 256 + threadIdx.x;
  if (i < n) p[i] = 0.f;
}

__global__ __launch_bounds__(256) void finalize_kernel(
    const float* __restrict__ colsum, float* __restrict__ out) {
  __shared__ float red[256];
  int t = threadIdx.x;
  float acc = 0.f;
  for (int i = t; i < NB * LSEQ; i += 256) {
    float aw = colsum[i] * (1.0f / 8192.0f) + 1e-8f;
    acc += -aw * __logf(aw);
  }
  red[t] = acc;
  __syncthreads();
  for (int s = 128; s > 0; s >>= 1) {
    if (t < s) red[t] += red[t + s];
    __syncthreads();
  }
  if (t == 0) {
    float me = red[0] * 0.25f;
    out[0] = 1.0f / (1.0f + __expf(-me));
  }
}

extern "C" void kernel_launch(void* const* d_in, const int* in_sizes, int n_in,
                              void* d_out, int out_size, void* d_ws, size_t ws_size,
                              hipStream_t stream) {
  const float* hs   = (const float*)d_in[0];   // [4,2048,1024]
  const float* wgt  = (const float*)d_in[1];   // [3072,1024]
  const float* bias = (const float*)d_in[2];   // [3072]
  float* out = (float*)d_out;
  char* ws = (char*)d_ws;

  unsigned short* Xb  = (unsigned short*)(ws);                        // 16 MB
  unsigned short* Wb  = (unsigned short*)(ws + (16u << 20));          // 4 MB
  unsigned short* Cqk = (unsigned short*)(ws + (20u << 20));          // 32 MB
  float* colsum = (float*)(ws + (54u << 20));                         // 32 KB
  float* Zbuf   = (float*)(ws + (54u << 20) + 32768);                 // 128 KB
  unsigned short* Ebuf = (unsigned short*)(ws + (56u << 20));         // 128 MiB

  f32_to_bf16_kernel<<<8192, 256, 0, stream>>>((const float4*)hs, (ushort4*)Xb);
  f32_to_bf16_kernel<<<2048, 256, 0, stream>>>((const float4*)wgt, (ushort4*)Wb);

  dim3 g1(16, 64);
  gemm_qk<<<g1, 256, 0, stream>>>(Xb, Wb, bias, Cqk);

  zero_kernel<<<160, 256, 0, stream>>>(colsum, NB * LSEQ + 16 * LSEQ);
  attn_exp<<<512, 256, 0, stream>>>(Cqk, Ebuf, Zbuf);
  attn_colsum2<<<512, 256, 0, stream>>>(Ebuf, Zbuf, colsum);
  finalize_kernel<<<1, 256, 0, stream>>>(colsum, out);
}